// Round 3
// baseline (118002.148 us; speedup 1.0000x reference)
//
#include <hip/hip_runtime.h>
#include <math.h>

#define W0F 30.0f
#define NPTS 32768

// f64 sin-path constants: sin(30 z) = sin(2*pi*frac_centered(z * 30/(2*pi)))
#define C_30_OVER_2PI 4.774648292756860070
#define C_2PI         6.283185307179586477

// ---- workspace layout (float offsets) ----
// Small param-derived buffers FIRST, big activation buffer LAST.
// Activations processed 2 latent-sets (t) at a time -> X is 2*32768*256.
#define OFF_M    0ull                   // 4 layers * 8 t * 65536
#define SZ_M     2097152ull
#define OFF_CB   (OFF_M + SZ_M)         // 4*8*256
#define SZ_CB    8192ull
#define OFF_AF   (OFF_CB + SZ_CB)       // 4*8*8192
#define SZ_AF    262144ull
#define OFF_BF   (OFF_AF + SZ_AF)
#define SZ_BF    262144ull
#define OFF_HB   (OFF_BF + SZ_BF)       // 4*8*256
#define SZ_HB    8192ull
#define OFF_NSC  (OFF_HB + SZ_HB)       // 4*256 + 1, pad to 2048
#define SZ_NSC   2048ull
#define OFF_X    (OFF_NSC + SZ_NSC)     // 2*32768*256 floats (reused per t-pair)
#define SZ_X     16777216ull
// total = 19,417,088 floats = 77.7 MB

// ---------------------------------------------------------------------------
// S1: per-row L1 scales + all latent-side GEMVs, f64 accumulation, f32 store.
// ---------------------------------------------------------------------------
__global__ __launch_bounds__(256) void setup1(
    const float* __restrict__ latents,
    const float* __restrict__ AwF, const float* __restrict__ AcF,
    const float* __restrict__ AwH, const float* __restrict__ AcH,
    const float* __restrict__ Bw,  const float* __restrict__ Bc,
    const float* __restrict__ hbw, const float* __restrict__ hbc,
    const float* __restrict__ wF,  const float* __restrict__ cF,
    const float* __restrict__ wH,  const float* __restrict__ cH,
    const float* __restrict__ wL,  const float* __restrict__ cL,
    float* __restrict__ AF, float* __restrict__ BFo,
    float* __restrict__ HBo, float* __restrict__ NSC)
{
    __shared__ float lat[1024];
    int tid = threadIdx.x;
    for (int j = tid; j < 1024; j += 256) lat[j] = latents[j];
    __syncthreads();
    int g = blockIdx.x * 256 + tid;
    if (g < 58464) {
        const float* src; float c; float* dst; int stride;
        if (g < 96) {
            src = AwF + g * 128; c = AcF[0]; dst = AF + g; stride = 8192;
        } else if (g < 24672) {
            int q = g - 96; int l = 1 + q / 8192;
            src = AwH + (size_t)q * 128; c = AcH[l - 1];
            dst = AF + (size_t)l * 8 * 8192 + (q % 8192); stride = 8192;
        } else if (g < 57440) {
            int q = g - 24672; int l = q / 8192;
            src = Bw + (size_t)q * 128; c = Bc[l];
            dst = BFo + (size_t)l * 8 * 8192 + (q % 8192); stride = 8192;
        } else {
            int q = g - 57440; int l = q / 256;
            src = hbw + (size_t)q * 128; c = hbc[l];
            dst = HBo + l * 8 * 256 + (q % 256); stride = 256;
        }
        double l1 = 0.0;
        double acc[8] = {0,0,0,0,0,0,0,0};
        for (int kk = 0; kk < 32; ++kk) {
            float4 w4 = ((const float4*)src)[kk];
            l1 += fabs((double)w4.x) + fabs((double)w4.y)
                + fabs((double)w4.z) + fabs((double)w4.w);
            int k = kk * 4;
            #pragma unroll
            for (int t = 0; t < 8; ++t) {
                const float* lp = &lat[t * 128 + k];
                acc[t] = fma((double)w4.x, (double)lp[0], acc[t]);
                acc[t] = fma((double)w4.y, (double)lp[1], acc[t]);
                acc[t] = fma((double)w4.z, (double)lp[2], acc[t]);
                acc[t] = fma((double)w4.w, (double)lp[3], acc[t]);
            }
        }
        double s = fmin(log1p(exp((double)c)) / l1, 1.0);
        #pragma unroll
        for (int t = 0; t < 8; ++t) dst[(size_t)t * stride] = (float)(acc[t] * s);
    } else if (g < 59489) {
        int h = g - 58464;
        if (h < 256) {
            const float* src = wF + h * 3;
            double l1 = fabs((double)src[0]) + fabs((double)src[1]) + fabs((double)src[2]);
            NSC[h] = (float)fmin(log1p(exp((double)cF[0])) / l1, 1.0);
        } else if (h < 1024) {
            int q = h - 256; int l = 1 + q / 256;
            const float* src = wH + (size_t)q * 256;
            double l1 = 0.0;
            for (int kk = 0; kk < 64; ++kk) {
                float4 w4 = ((const float4*)src)[kk];
                l1 += fabs((double)w4.x) + fabs((double)w4.y)
                    + fabs((double)w4.z) + fabs((double)w4.w);
            }
            NSC[256 + q] = (float)fmin(log1p(exp((double)cH[l - 1])) / l1, 1.0);
        } else {
            double l1 = 0.0;
            for (int kk = 0; kk < 64; ++kk) {
                float4 w4 = ((const float4*)wL)[kk];
                l1 += fabs((double)w4.x) + fabs((double)w4.y)
                    + fabs((double)w4.z) + fabs((double)w4.w);
            }
            NSC[1024] = (float)fmin(log1p(exp((double)cL[0])) / l1, 1.0);
        }
    }
}

// ---------------------------------------------------------------------------
// S2: M[l][t][i][o] = W[o,i]*s[o] + sum_r A[i,r]B[r,o]  (f64 acc, f32 store)
// CB[l][t][o] = b[o] + hyperbias[t][o].
// ---------------------------------------------------------------------------
__global__ __launch_bounds__(256) void setup2(
    const float* __restrict__ wF, const float* __restrict__ bF,
    const float* __restrict__ wH, const float* __restrict__ bH,
    const float* __restrict__ AF, const float* __restrict__ BFi,
    const float* __restrict__ HBi, const float* __restrict__ NSC,
    float* __restrict__ Mb, float* __restrict__ CBb)
{
    int b = blockIdx.x; int t = b / 49; int rem = b % 49;
    int o = threadIdx.x;
    int l, i0, ni;
    if (rem == 0) { l = 0; i0 = 0; ni = 3; }
    else { l = 1 + (rem - 1) / 16; i0 = ((rem - 1) % 16) * 16; ni = 16; }
    size_t ltb = (size_t)(l * 8 + t);
    const float* af = AF + ltb * 8192;
    const float* bf = BFi + ltb * 8192;
    double sc = (double)NSC[l * 256 + o];
    float bcol[32];
    #pragma unroll
    for (int r = 0; r < 32; ++r) bcol[r] = bf[r * 256 + o];
    for (int ii = 0; ii < ni; ++ii) {
        int i = i0 + ii;
        float wv = (l == 0) ? wF[o * 3 + i] : wH[(size_t)((l - 1) * 256 + o) * 256 + i];
        double m = (double)wv * sc;
        #pragma unroll
        for (int r = 0; r < 32; ++r)
            m = fma((double)af[i * 32 + r], (double)bcol[r], m);
        Mb[ltb * 65536 + (size_t)i * 256 + o] = (float)m;
    }
    if (rem == 0 || ((rem - 1) % 16) == 0) {
        double bb = (l == 0) ? (double)bF[o] : (double)bH[(l - 1) * 256 + o];
        CBb[ltb * 256 + o] = (float)(bb + (double)HBi[ltb * 256 + o]);
    }
}

// precise activation: sin(30*z) via f64 range reduction + f32 sin on [-pi,pi]
__device__ __forceinline__ float sin30(double z) {
    double u = z * C_30_OVER_2PI;
    double r = u - rint(u);
    return sinf((float)(r * C_2PI));
}

// ---------------------------------------------------------------------------
// L0: x = sin(30*(coords @ M0 + cb)), f64 arithmetic per element (K=3).
// grid 2048 = 2 t * 1024 row-blocks of 32 rows.
// ---------------------------------------------------------------------------
__global__ __launch_bounds__(256) void layer0_k(
    const float* __restrict__ coords, const float* __restrict__ Mb,
    const float* __restrict__ CBb, float* __restrict__ X, int tbase)
{
    __shared__ float Ms[3][256];
    __shared__ float cbs[256];
    int tid = threadIdx.x;
    int tl = blockIdx.x >> 10; int rb = blockIdx.x & 1023;
    int t = tbase + tl;
    const float* Mt = Mb + (size_t)t * 65536;
    Ms[0][tid] = Mt[tid]; Ms[1][tid] = Mt[256 + tid]; Ms[2][tid] = Mt[512 + tid];
    cbs[tid] = CBb[t * 256 + tid];
    __syncthreads();
    int r = rb * 32 + (tid >> 3); int lane8 = tid & 7;
    const float* cp = coords + ((size_t)t * NPTS + r) * 3;
    double c0 = (double)cp[0], c1 = (double)cp[1], c2 = (double)cp[2];
    float* xo = X + ((size_t)tl * NPTS + r) * 256;
    #pragma unroll
    for (int j = 0; j < 8; ++j) {
        int col = 4 * lane8 + 32 * j;
        float4 v;
        #pragma unroll
        for (int e = 0; e < 4; ++e) {
            double z = (double)cbs[col + e];
            z = fma(c0, (double)Ms[0][col + e], z);
            z = fma(c1, (double)Ms[1][col + e], z);
            z = fma(c2, (double)Ms[2][col + e], z);
            (&v.x)[e] = sin30(z);
        }
        *(float4*)(xo + col) = v;
    }
}

// ---------------------------------------------------------------------------
// Hidden layer: X[rows] = sin(30*(X[rows] @ M[l][t] + cb)) IN PLACE, f64 acc.
// WG tile = 64 rows x 256 cols (full width -> rows exclusively owned).
// Thread tile 4x16 -> double acc[4][16] = 128 VGPRs. BK=16.
// As transposed [k][row] pad 68 (16B-aligned b128 reads, mild store conflict).
// Bs [k][256] with 16B-chunk XOR swizzle: phys = ch ^ ((ch>>3)&7) so the
// stride-64B b128 fragment reads are bank-conflict-free.
// ---------------------------------------------------------------------------
__global__ __launch_bounds__(256, 2) void gemm_sin(
    float* __restrict__ X, const float* __restrict__ Mb,
    const float* __restrict__ CBb, int l, int tbase)
{
    __shared__ float As[16][68];
    __shared__ float Bs[16][256];
    __shared__ float cbs[256];
    int tid = threadIdx.x;
    int tl = blockIdx.x >> 9; int rb = blockIdx.x & 511;
    size_t ltb = (size_t)(l * 8 + tbase + tl);
    const float* Mt = Mb + ltb * 65536;
    float* Xt = X + ((size_t)tl * NPTS + rb * 64) * 256;
    cbs[tid] = CBb[ltb * 256 + tid];
    int tr = tid >> 4, tc = tid & 15;   // 16 row-groups x4, 16 col-groups x16
    int arow = tid >> 2;                // 0..63
    int ak4  = (tid & 3) * 4;
    int bch  = tid & 63;                // B chunk-in-row
    int pch  = bch ^ ((bch >> 3) & 7);  // swizzled physical chunk
    int br0  = tid >> 6;                // 0..3 -> rows br0+{0,4,8,12}
    int sw   = (tc >> 1) & 7;           // read-side swizzle key
    double acc[4][16] = {};
    for (int kb = 0; kb < 16; ++kb) {
        float4 a0 = *(const float4*)(Xt + (size_t)arow * 256 + kb * 16 + ak4);
        const float* Bg = Mt + (size_t)kb * 16 * 256 + bch * 4;
        float4 b0 = *(const float4*)(Bg + (br0 +  0) * 256);
        float4 b1 = *(const float4*)(Bg + (br0 +  4) * 256);
        float4 b2 = *(const float4*)(Bg + (br0 +  8) * 256);
        float4 b3 = *(const float4*)(Bg + (br0 + 12) * 256);
        __syncthreads();   // previous iter's LDS reads done before overwrite
        As[ak4+0][arow] = a0.x; As[ak4+1][arow] = a0.y;
        As[ak4+2][arow] = a0.z; As[ak4+3][arow] = a0.w;
        *(float4*)&Bs[br0 +  0][pch * 4] = b0;
        *(float4*)&Bs[br0 +  4][pch * 4] = b1;
        *(float4*)&Bs[br0 +  8][pch * 4] = b2;
        *(float4*)&Bs[br0 + 12][pch * 4] = b3;
        __syncthreads();
        #pragma unroll
        for (int k = 0; k < 16; ++k) {
            float4 af = *(const float4*)&As[k][tr * 4];
            double av[4] = {(double)af.x, (double)af.y, (double)af.z, (double)af.w};
            double bv[16];
            #pragma unroll
            for (int m = 0; m < 4; ++m) {
                int ch = (4 * tc + m) ^ sw;
                float4 bf = *(const float4*)&Bs[k][ch * 4];
                bv[4*m+0] = (double)bf.x; bv[4*m+1] = (double)bf.y;
                bv[4*m+2] = (double)bf.z; bv[4*m+3] = (double)bf.w;
            }
            #pragma unroll
            for (int i = 0; i < 4; ++i)
                #pragma unroll
                for (int j = 0; j < 16; ++j)
                    acc[i][j] = fma(av[i], bv[j], acc[i][j]);
        }
    }
    #pragma unroll
    for (int i = 0; i < 4; ++i) {
        float* orow = Xt + (size_t)(tr * 4 + i) * 256 + tc * 16;
        #pragma unroll
        for (int j4 = 0; j4 < 4; ++j4) {
            float4 v;
            #pragma unroll
            for (int e = 0; e < 4; ++e) {
                int j = j4 * 4 + e;
                double z = acc[i][j] + (double)cbs[tc * 16 + j];
                (&v.x)[e] = sin30(z);
            }
            *(float4*)(orow + j4 * 4) = v;
        }
    }
}

// ---------------------------------------------------------------------------
// Final: out[row] = (x_row . w_last)*scale + b_last, f64 dot. One wave per row.
// ---------------------------------------------------------------------------
__global__ __launch_bounds__(256) void final_k(
    const float* __restrict__ X, const float* __restrict__ wl,
    const float* __restrict__ bl, const float* __restrict__ NSC,
    float* __restrict__ out, int tbase)
{
    int tid = threadIdx.x; int w = tid >> 6; int lane = tid & 63;
    size_t row = (size_t)blockIdx.x * 4 + w;      // local row within 2 t's
    double ls = (double)NSC[1024];
    float4 wv = ((const float4*)wl)[lane];
    float4 xv = *(const float4*)(X + row * 256 + lane * 4);
    double d = 0.0;
    d = fma((double)wv.x, (double)xv.x, d);
    d = fma((double)wv.y, (double)xv.y, d);
    d = fma((double)wv.z, (double)xv.z, d);
    d = fma((double)wv.w, (double)xv.w, d);
    d *= ls;
    #pragma unroll
    for (int off = 32; off > 0; off >>= 1) d += __shfl_down(d, off, 64);
    if (lane == 0) out[(size_t)tbase * NPTS + row] = (float)(d + (double)bl[0]);
}

extern "C" void kernel_launch(void* const* d_in, const int* in_sizes, int n_in,
                              void* d_out, int out_size, void* d_ws, size_t ws_size,
                              hipStream_t stream)
{
    const float* coords     = (const float*)d_in[0];
    const float* latents    = (const float*)d_in[1];
    const float* nf_w_first = (const float*)d_in[2];
    const float* nf_b_first = (const float*)d_in[3];
    const float* nf_c_first = (const float*)d_in[4];
    const float* nf_w_hid   = (const float*)d_in[5];
    const float* nf_b_hid   = (const float*)d_in[6];
    const float* nf_c_hid   = (const float*)d_in[7];
    const float* nf_w_last  = (const float*)d_in[8];
    const float* nf_b_last  = (const float*)d_in[9];
    const float* nf_c_last  = (const float*)d_in[10];
    const float* Aw_first   = (const float*)d_in[11];
    const float* Ac_first   = (const float*)d_in[12];
    const float* Aw_hid     = (const float*)d_in[13];
    const float* Ac_hid     = (const float*)d_in[14];
    const float* Bw         = (const float*)d_in[15];
    const float* Bc         = (const float*)d_in[16];
    const float* hbw        = (const float*)d_in[17];
    const float* hbc        = (const float*)d_in[18];

    float* ws  = (float*)d_ws;
    float* Mb  = ws + OFF_M;
    float* CBb = ws + OFF_CB;
    float* AF  = ws + OFF_AF;
    float* BFb = ws + OFF_BF;
    float* HBb = ws + OFF_HB;
    float* NSC = ws + OFF_NSC;
    float* X   = ws + OFF_X;
    float* out = (float*)d_out;

    setup1<<<233, 256, 0, stream>>>(latents, Aw_first, Ac_first, Aw_hid, Ac_hid,
                                    Bw, Bc, hbw, hbc,
                                    nf_w_first, nf_c_first, nf_w_hid, nf_c_hid,
                                    nf_w_last, nf_c_last,
                                    AF, BFb, HBb, NSC);
    setup2<<<392, 256, 0, stream>>>(nf_w_first, nf_b_first, nf_w_hid, nf_b_hid,
                                    AF, BFb, HBb, NSC, Mb, CBb);
    for (int tbase = 0; tbase < 8; tbase += 2) {
        layer0_k<<<2048, 256, 0, stream>>>(coords, Mb, CBb, X, tbase);
        for (int l = 1; l <= 3; ++l)
            gemm_sin<<<1024, 256, 0, stream>>>(X, Mb, CBb, l, tbase);
        final_k<<<16384, 256, 0, stream>>>(X, nf_w_last, nf_b_last, NSC, out, tbase);
    }
}

// Round 4
// 2878.243 us; speedup vs baseline: 40.9980x; 40.9980x over previous
//
#include <hip/hip_runtime.h>
#include <math.h>

#define W0F 30.0f
#define NPTS 32768

// f64 sin-path constants: sin(30 z) = sin(2*pi*frac_centered(z * 30/(2*pi)))
#define C_30_OVER_2PI 4.774648292756860070
#define C_2PI         6.283185307179586477

// ---- workspace layout (float offsets) ----
#define OFF_M    0ull                   // 4 layers * 8 t * 65536
#define SZ_M     2097152ull
#define OFF_CB   (OFF_M + SZ_M)         // 4*8*256
#define SZ_CB    8192ull
#define OFF_AF   (OFF_CB + SZ_CB)       // 4*8*8192
#define SZ_AF    262144ull
#define OFF_BF   (OFF_AF + SZ_AF)
#define SZ_BF    262144ull
#define OFF_HB   (OFF_BF + SZ_BF)       // 4*8*256
#define SZ_HB    8192ull
#define OFF_NSC  (OFF_HB + SZ_HB)       // 4*256 + 1, pad to 2048
#define SZ_NSC   2048ull
#define OFF_X    (OFF_NSC + SZ_NSC)     // 2*32768*256 floats (reused per t-pair)
#define SZ_X     16777216ull

// ---------------------------------------------------------------------------
// S1: per-row L1 scales + all latent-side GEMVs, f64 accumulation, f32 store.
// ---------------------------------------------------------------------------
__global__ __launch_bounds__(256) void setup1(
    const float* __restrict__ latents,
    const float* __restrict__ AwF, const float* __restrict__ AcF,
    const float* __restrict__ AwH, const float* __restrict__ AcH,
    const float* __restrict__ Bw,  const float* __restrict__ Bc,
    const float* __restrict__ hbw, const float* __restrict__ hbc,
    const float* __restrict__ wF,  const float* __restrict__ cF,
    const float* __restrict__ wH,  const float* __restrict__ cH,
    const float* __restrict__ wL,  const float* __restrict__ cL,
    float* __restrict__ AF, float* __restrict__ BFo,
    float* __restrict__ HBo, float* __restrict__ NSC)
{
    __shared__ float lat[1024];
    int tid = threadIdx.x;
    for (int j = tid; j < 1024; j += 256) lat[j] = latents[j];
    __syncthreads();
    int g = blockIdx.x * 256 + tid;
    if (g < 58464) {
        const float* src; float c; float* dst; int stride;
        if (g < 96) {
            src = AwF + g * 128; c = AcF[0]; dst = AF + g; stride = 8192;
        } else if (g < 24672) {
            int q = g - 96; int l = 1 + q / 8192;
            src = AwH + (size_t)q * 128; c = AcH[l - 1];
            dst = AF + (size_t)l * 8 * 8192 + (q % 8192); stride = 8192;
        } else if (g < 57440) {
            int q = g - 24672; int l = q / 8192;
            src = Bw + (size_t)q * 128; c = Bc[l];
            dst = BFo + (size_t)l * 8 * 8192 + (q % 8192); stride = 8192;
        } else {
            int q = g - 57440; int l = q / 256;
            src = hbw + (size_t)q * 128; c = hbc[l];
            dst = HBo + l * 8 * 256 + (q % 256); stride = 256;
        }
        double l1 = 0.0;
        double acc[8] = {0,0,0,0,0,0,0,0};
        for (int kk = 0; kk < 32; ++kk) {
            float4 w4 = ((const float4*)src)[kk];
            l1 += fabs((double)w4.x) + fabs((double)w4.y)
                + fabs((double)w4.z) + fabs((double)w4.w);
            int k = kk * 4;
            #pragma unroll
            for (int t = 0; t < 8; ++t) {
                const float* lp = &lat[t * 128 + k];
                acc[t] = fma((double)w4.x, (double)lp[0], acc[t]);
                acc[t] = fma((double)w4.y, (double)lp[1], acc[t]);
                acc[t] = fma((double)w4.z, (double)lp[2], acc[t]);
                acc[t] = fma((double)w4.w, (double)lp[3], acc[t]);
            }
        }
        double s = fmin(log1p(exp((double)c)) / l1, 1.0);
        #pragma unroll
        for (int t = 0; t < 8; ++t) dst[(size_t)t * stride] = (float)(acc[t] * s);
    } else if (g < 59489) {
        int h = g - 58464;
        if (h < 256) {
            const float* src = wF + h * 3;
            double l1 = fabs((double)src[0]) + fabs((double)src[1]) + fabs((double)src[2]);
            NSC[h] = (float)fmin(log1p(exp((double)cF[0])) / l1, 1.0);
        } else if (h < 1024) {
            int q = h - 256; int l = 1 + q / 256;
            const float* src = wH + (size_t)q * 256;
            double l1 = 0.0;
            for (int kk = 0; kk < 64; ++kk) {
                float4 w4 = ((const float4*)src)[kk];
                l1 += fabs((double)w4.x) + fabs((double)w4.y)
                    + fabs((double)w4.z) + fabs((double)w4.w);
            }
            NSC[256 + q] = (float)fmin(log1p(exp((double)cH[l - 1])) / l1, 1.0);
        } else {
            double l1 = 0.0;
            for (int kk = 0; kk < 64; ++kk) {
                float4 w4 = ((const float4*)wL)[kk];
                l1 += fabs((double)w4.x) + fabs((double)w4.y)
                    + fabs((double)w4.z) + fabs((double)w4.w);
            }
            NSC[1024] = (float)fmin(log1p(exp((double)cL[0])) / l1, 1.0);
        }
    }
}

// ---------------------------------------------------------------------------
// S2: M[l][t][i][o] = W[o,i]*s[o] + sum_r A[i,r]B[r,o]  (f64 acc, f32 store)
// ---------------------------------------------------------------------------
__global__ __launch_bounds__(256) void setup2(
    const float* __restrict__ wF, const float* __restrict__ bF,
    const float* __restrict__ wH, const float* __restrict__ bH,
    const float* __restrict__ AF, const float* __restrict__ BFi,
    const float* __restrict__ HBi, const float* __restrict__ NSC,
    float* __restrict__ Mb, float* __restrict__ CBb)
{
    int b = blockIdx.x; int t = b / 49; int rem = b % 49;
    int o = threadIdx.x;
    int l, i0, ni;
    if (rem == 0) { l = 0; i0 = 0; ni = 3; }
    else { l = 1 + (rem - 1) / 16; i0 = ((rem - 1) % 16) * 16; ni = 16; }
    size_t ltb = (size_t)(l * 8 + t);
    const float* af = AF + ltb * 8192;
    const float* bf = BFi + ltb * 8192;
    double sc = (double)NSC[l * 256 + o];
    float bcol[32];
    #pragma unroll
    for (int r = 0; r < 32; ++r) bcol[r] = bf[r * 256 + o];
    for (int ii = 0; ii < ni; ++ii) {
        int i = i0 + ii;
        float wv = (l == 0) ? wF[o * 3 + i] : wH[(size_t)((l - 1) * 256 + o) * 256 + i];
        double m = (double)wv * sc;
        #pragma unroll
        for (int r = 0; r < 32; ++r)
            m = fma((double)af[i * 32 + r], (double)bcol[r], m);
        Mb[ltb * 65536 + (size_t)i * 256 + o] = (float)m;
    }
    if (rem == 0 || ((rem - 1) % 16) == 0) {
        double bb = (l == 0) ? (double)bF[o] : (double)bH[(l - 1) * 256 + o];
        CBb[ltb * 256 + o] = (float)(bb + (double)HBi[ltb * 256 + o]);
    }
}

// precise activation: sin(30*z) via f64 range reduction + f32 sin on [-pi,pi]
__device__ __forceinline__ float sin30(double z) {
    double u = z * C_30_OVER_2PI;
    double r = u - rint(u);
    return sinf((float)(r * C_2PI));
}

// ---------------------------------------------------------------------------
// L0: x = sin(30*(coords @ M0 + cb)), f64 per element (K=3). No address-taken
// locals (scratch hazard) — explicit .x/.y/.z/.w.
// ---------------------------------------------------------------------------
__global__ __launch_bounds__(256) void layer0_k(
    const float* __restrict__ coords, const float* __restrict__ Mb,
    const float* __restrict__ CBb, float* __restrict__ X, int tbase)
{
    __shared__ float Ms[3][256];
    __shared__ float cbs[256];
    int tid = threadIdx.x;
    int tl = blockIdx.x >> 10; int rb = blockIdx.x & 1023;
    int t = tbase + tl;
    const float* Mt = Mb + (size_t)t * 65536;
    Ms[0][tid] = Mt[tid]; Ms[1][tid] = Mt[256 + tid]; Ms[2][tid] = Mt[512 + tid];
    cbs[tid] = CBb[t * 256 + tid];
    __syncthreads();
    int r = rb * 32 + (tid >> 3); int lane8 = tid & 7;
    const float* cp = coords + ((size_t)t * NPTS + r) * 3;
    double c0 = (double)cp[0], c1 = (double)cp[1], c2 = (double)cp[2];
    float* xo = X + ((size_t)tl * NPTS + r) * 256;
#define L0E(col) sin30(fma(c2, (double)Ms[2][col], fma(c1, (double)Ms[1][col], \
                  fma(c0, (double)Ms[0][col], (double)cbs[col]))))
    #pragma unroll
    for (int j = 0; j < 8; ++j) {
        int col = 4 * lane8 + 32 * j;
        float4 v;
        v.x = L0E(col + 0);
        v.y = L0E(col + 1);
        v.z = L0E(col + 2);
        v.w = L0E(col + 3);
        *(float4*)(xo + col) = v;
    }
#undef L0E
}

// ---------------------------------------------------------------------------
// Hidden layer: X[rows] = sin(30*(X[rows] @ M[l][t] + cb)) IN PLACE, f64 acc.
// WG tile 64 rows x 256 cols. Thread tile 4x16.
// CRITICAL: accumulators split into four 128-B arrays (acc0..acc3[16]) so
// SROA promotes them to VGPRs — round 3's acc[4][16] (512 B) stayed in
// scratch (VGPR_Count=36, 50 GB HBM/dispatch, VALUBusy 1.7%).
// ---------------------------------------------------------------------------
__global__ __launch_bounds__(256, 2) void gemm_sin(
    float* __restrict__ X, const float* __restrict__ Mb,
    const float* __restrict__ CBb, int l, int tbase)
{
    __shared__ float As[16][68];
    __shared__ float Bs[16][256];
    __shared__ float cbs[256];
    int tid = threadIdx.x;
    int tl = blockIdx.x >> 9; int rb = blockIdx.x & 511;
    size_t ltb = (size_t)(l * 8 + tbase + tl);
    const float* Mt = Mb + ltb * 65536;
    float* Xt = X + ((size_t)tl * NPTS + rb * 64) * 256;
    cbs[tid] = CBb[ltb * 256 + tid];
    int tr = tid >> 4, tc = tid & 15;   // 16 row-groups x4, 16 col-groups x16
    int arow = tid >> 2;                // 0..63
    int ak4  = (tid & 3) * 4;
    int bch  = tid & 63;                // B chunk-in-row (16B chunks)
    int pch  = bch ^ ((bch >> 3) & 7);  // swizzled physical chunk
    int br0  = tid >> 6;                // 0..3 -> rows br0+{0,4,8,12}
    int sw   = (tc >> 1) & 7;           // read-side swizzle key
    double acc0[16] = {}; double acc1[16] = {};
    double acc2[16] = {}; double acc3[16] = {};
    for (int kb = 0; kb < 16; ++kb) {
        float4 a0 = *(const float4*)(Xt + (size_t)arow * 256 + kb * 16 + ak4);
        const float* Bg = Mt + (size_t)kb * 16 * 256 + bch * 4;
        float4 b0 = *(const float4*)(Bg + (br0 +  0) * 256);
        float4 b1 = *(const float4*)(Bg + (br0 +  4) * 256);
        float4 b2 = *(const float4*)(Bg + (br0 +  8) * 256);
        float4 b3 = *(const float4*)(Bg + (br0 + 12) * 256);
        __syncthreads();   // previous iter's LDS reads done before overwrite
        As[ak4+0][arow] = a0.x; As[ak4+1][arow] = a0.y;
        As[ak4+2][arow] = a0.z; As[ak4+3][arow] = a0.w;
        *(float4*)&Bs[br0 +  0][pch * 4] = b0;
        *(float4*)&Bs[br0 +  4][pch * 4] = b1;
        *(float4*)&Bs[br0 +  8][pch * 4] = b2;
        *(float4*)&Bs[br0 + 12][pch * 4] = b3;
        __syncthreads();
        #pragma unroll
        for (int k = 0; k < 16; ++k) {
            float4 af = *(const float4*)&As[k][tr * 4];
            double av0 = (double)af.x, av1 = (double)af.y;
            double av2 = (double)af.z, av3 = (double)af.w;
            #pragma unroll
            for (int m = 0; m < 4; ++m) {
                int ch = (4 * tc + m) ^ sw;
                float4 bf = *(const float4*)&Bs[k][ch * 4];
                double bv0 = (double)bf.x, bv1 = (double)bf.y;
                double bv2 = (double)bf.z, bv3 = (double)bf.w;
                acc0[4*m+0] = fma(av0, bv0, acc0[4*m+0]);
                acc0[4*m+1] = fma(av0, bv1, acc0[4*m+1]);
                acc0[4*m+2] = fma(av0, bv2, acc0[4*m+2]);
                acc0[4*m+3] = fma(av0, bv3, acc0[4*m+3]);
                acc1[4*m+0] = fma(av1, bv0, acc1[4*m+0]);
                acc1[4*m+1] = fma(av1, bv1, acc1[4*m+1]);
                acc1[4*m+2] = fma(av1, bv2, acc1[4*m+2]);
                acc1[4*m+3] = fma(av1, bv3, acc1[4*m+3]);
                acc2[4*m+0] = fma(av2, bv0, acc2[4*m+0]);
                acc2[4*m+1] = fma(av2, bv1, acc2[4*m+1]);
                acc2[4*m+2] = fma(av2, bv2, acc2[4*m+2]);
                acc2[4*m+3] = fma(av2, bv3, acc2[4*m+3]);
                acc3[4*m+0] = fma(av3, bv0, acc3[4*m+0]);
                acc3[4*m+1] = fma(av3, bv1, acc3[4*m+1]);
                acc3[4*m+2] = fma(av3, bv2, acc3[4*m+2]);
                acc3[4*m+3] = fma(av3, bv3, acc3[4*m+3]);
            }
        }
    }
#define EPI(I, ACC)                                                            \
    {                                                                          \
        float* orow = Xt + (size_t)(tr * 4 + I) * 256 + tc * 16;               \
        _Pragma("unroll")                                                      \
        for (int j4 = 0; j4 < 4; ++j4) {                                       \
            float4 v;                                                          \
            v.x = sin30(ACC[4*j4+0] + (double)cbs[tc*16 + 4*j4 + 0]);          \
            v.y = sin30(ACC[4*j4+1] + (double)cbs[tc*16 + 4*j4 + 1]);          \
            v.z = sin30(ACC[4*j4+2] + (double)cbs[tc*16 + 4*j4 + 2]);          \
            v.w = sin30(ACC[4*j4+3] + (double)cbs[tc*16 + 4*j4 + 3]);          \
            *(float4*)(orow + j4 * 4) = v;                                     \
        }                                                                      \
    }
    EPI(0, acc0)
    EPI(1, acc1)
    EPI(2, acc2)
    EPI(3, acc3)
#undef EPI
}

// ---------------------------------------------------------------------------
// Final: out[row] = (x_row . w_last)*scale + b_last, f64 dot. One wave per row.
// ---------------------------------------------------------------------------
__global__ __launch_bounds__(256) void final_k(
    const float* __restrict__ X, const float* __restrict__ wl,
    const float* __restrict__ bl, const float* __restrict__ NSC,
    float* __restrict__ out, int tbase)
{
    int tid = threadIdx.x; int w = tid >> 6; int lane = tid & 63;
    size_t row = (size_t)blockIdx.x * 4 + w;      // local row within 2 t's
    double ls = (double)NSC[1024];
    float4 wv = ((const float4*)wl)[lane];
    float4 xv = *(const float4*)(X + row * 256 + lane * 4);
    double d = 0.0;
    d = fma((double)wv.x, (double)xv.x, d);
    d = fma((double)wv.y, (double)xv.y, d);
    d = fma((double)wv.z, (double)xv.z, d);
    d = fma((double)wv.w, (double)xv.w, d);
    d *= ls;
    #pragma unroll
    for (int off = 32; off > 0; off >>= 1) d += __shfl_down(d, off, 64);
    if (lane == 0) out[(size_t)tbase * NPTS + row] = (float)(d + (double)bl[0]);
}

extern "C" void kernel_launch(void* const* d_in, const int* in_sizes, int n_in,
                              void* d_out, int out_size, void* d_ws, size_t ws_size,
                              hipStream_t stream)
{
    const float* coords     = (const float*)d_in[0];
    const float* latents    = (const float*)d_in[1];
    const float* nf_w_first = (const float*)d_in[2];
    const float* nf_b_first = (const float*)d_in[3];
    const float* nf_c_first = (const float*)d_in[4];
    const float* nf_w_hid   = (const float*)d_in[5];
    const float* nf_b_hid   = (const float*)d_in[6];
    const float* nf_c_hid   = (const float*)d_in[7];
    const float* nf_w_last  = (const float*)d_in[8];
    const float* nf_b_last  = (const float*)d_in[9];
    const float* nf_c_last  = (const float*)d_in[10];
    const float* Aw_first   = (const float*)d_in[11];
    const float* Ac_first   = (const float*)d_in[12];
    const float* Aw_hid     = (const float*)d_in[13];
    const float* Ac_hid     = (const float*)d_in[14];
    const float* Bw         = (const float*)d_in[15];
    const float* Bc         = (const float*)d_in[16];
    const float* hbw        = (const float*)d_in[17];
    const float* hbc        = (const float*)d_in[18];

    float* ws  = (float*)d_ws;
    float* Mb  = ws + OFF_M;
    float* CBb = ws + OFF_CB;
    float* AF  = ws + OFF_AF;
    float* BFb = ws + OFF_BF;
    float* HBb = ws + OFF_HB;
    float* NSC = ws + OFF_NSC;
    float* X   = ws + OFF_X;
    float* out = (float*)d_out;

    setup1<<<233, 256, 0, stream>>>(latents, Aw_first, Ac_first, Aw_hid, Ac_hid,
                                    Bw, Bc, hbw, hbc,
                                    nf_w_first, nf_c_first, nf_w_hid, nf_c_hid,
                                    nf_w_last, nf_c_last,
                                    AF, BFb, HBb, NSC);
    setup2<<<392, 256, 0, stream>>>(nf_w_first, nf_b_first, nf_w_hid, nf_b_hid,
                                    AF, BFb, HBb, NSC, Mb, CBb);
    for (int tbase = 0; tbase < 8; tbase += 2) {
        layer0_k<<<2048, 256, 0, stream>>>(coords, Mb, CBb, X, tbase);
        for (int l = 1; l <= 3; ++l)
            gemm_sin<<<1024, 256, 0, stream>>>(X, Mb, CBb, l, tbase);
        final_k<<<16384, 256, 0, stream>>>(X, nf_w_last, nf_b_last, NSC, out, tbase);
    }
}

// Round 6
// 2328.381 us; speedup vs baseline: 50.6799x; 1.2362x over previous
//
#include <hip/hip_runtime.h>
#include <math.h>

#define W0F 30.0f
#define NPTS 32768

// f64 sin-path constants: sin(30 z) = sin(2*pi*frac_centered(z * 30/(2*pi)))
#define C_30_OVER_2PI 4.774648292756860070
#define C_2PI         6.283185307179586477

typedef double v4d __attribute__((ext_vector_type(4)));

// ---- workspace layout (float offsets) ----
#define OFF_M    0ull                   // 4 layers * 8 t * 65536
#define SZ_M     2097152ull
#define OFF_CB   (OFF_M + SZ_M)         // 4*8*256
#define SZ_CB    8192ull
#define OFF_AF   (OFF_CB + SZ_CB)       // 4*8*8192
#define SZ_AF    262144ull
#define OFF_BF   (OFF_AF + SZ_AF)
#define SZ_BF    262144ull
#define OFF_HB   (OFF_BF + SZ_BF)       // 4*8*256
#define SZ_HB    8192ull
#define OFF_NSC  (OFF_HB + SZ_HB)       // 4*256 + 1, pad to 2048
#define SZ_NSC   2048ull
#define OFF_X    (OFF_NSC + SZ_NSC)     // 2*32768*256 floats (reused per t-pair)
#define SZ_X     16777216ull

// ---------------------------------------------------------------------------
// S1: per-row L1 scales + all latent-side GEMVs, f64 accumulation, f32 store.
// ---------------------------------------------------------------------------
__global__ __launch_bounds__(256) void setup1(
    const float* __restrict__ latents,
    const float* __restrict__ AwF, const float* __restrict__ AcF,
    const float* __restrict__ AwH, const float* __restrict__ AcH,
    const float* __restrict__ Bw,  const float* __restrict__ Bc,
    const float* __restrict__ hbw, const float* __restrict__ hbc,
    const float* __restrict__ wF,  const float* __restrict__ cF,
    const float* __restrict__ wH,  const float* __restrict__ cH,
    const float* __restrict__ wL,  const float* __restrict__ cL,
    float* __restrict__ AF, float* __restrict__ BFo,
    float* __restrict__ HBo, float* __restrict__ NSC)
{
    __shared__ float lat[1024];
    int tid = threadIdx.x;
    for (int j = tid; j < 1024; j += 256) lat[j] = latents[j];
    __syncthreads();
    int g = blockIdx.x * 256 + tid;
    if (g < 58464) {
        const float* src; float c; float* dst; int stride;
        if (g < 96) {
            src = AwF + g * 128; c = AcF[0]; dst = AF + g; stride = 8192;
        } else if (g < 24672) {
            int q = g - 96; int l = 1 + q / 8192;
            src = AwH + (size_t)q * 128; c = AcH[l - 1];
            dst = AF + (size_t)l * 8 * 8192 + (q % 8192); stride = 8192;
        } else if (g < 57440) {
            int q = g - 24672; int l = q / 8192;
            src = Bw + (size_t)q * 128; c = Bc[l];
            dst = BFo + (size_t)l * 8 * 8192 + (q % 8192); stride = 8192;
        } else {
            int q = g - 57440; int l = q / 256;
            src = hbw + (size_t)q * 128; c = hbc[l];
            dst = HBo + l * 8 * 256 + (q % 256); stride = 256;
        }
        double l1 = 0.0;
        double acc[8] = {0,0,0,0,0,0,0,0};
        for (int kk = 0; kk < 32; ++kk) {
            float4 w4 = ((const float4*)src)[kk];
            l1 += fabs((double)w4.x) + fabs((double)w4.y)
                + fabs((double)w4.z) + fabs((double)w4.w);
            int k = kk * 4;
            #pragma unroll
            for (int t = 0; t < 8; ++t) {
                const float* lp = &lat[t * 128 + k];
                acc[t] = fma((double)w4.x, (double)lp[0], acc[t]);
                acc[t] = fma((double)w4.y, (double)lp[1], acc[t]);
                acc[t] = fma((double)w4.z, (double)lp[2], acc[t]);
                acc[t] = fma((double)w4.w, (double)lp[3], acc[t]);
            }
        }
        double s = fmin(log1p(exp((double)c)) / l1, 1.0);
        #pragma unroll
        for (int t = 0; t < 8; ++t) dst[(size_t)t * stride] = (float)(acc[t] * s);
    } else if (g < 59489) {
        int h = g - 58464;
        if (h < 256) {
            const float* src = wF + h * 3;
            double l1 = fabs((double)src[0]) + fabs((double)src[1]) + fabs((double)src[2]);
            NSC[h] = (float)fmin(log1p(exp((double)cF[0])) / l1, 1.0);
        } else if (h < 1024) {
            int q = h - 256; int l = 1 + q / 256;
            const float* src = wH + (size_t)q * 256;
            double l1 = 0.0;
            for (int kk = 0; kk < 64; ++kk) {
                float4 w4 = ((const float4*)src)[kk];
                l1 += fabs((double)w4.x) + fabs((double)w4.y)
                    + fabs((double)w4.z) + fabs((double)w4.w);
            }
            NSC[256 + q] = (float)fmin(log1p(exp((double)cH[l - 1])) / l1, 1.0);
        } else {
            double l1 = 0.0;
            for (int kk = 0; kk < 64; ++kk) {
                float4 w4 = ((const float4*)wL)[kk];
                l1 += fabs((double)w4.x) + fabs((double)w4.y)
                    + fabs((double)w4.z) + fabs((double)w4.w);
            }
            NSC[1024] = (float)fmin(log1p(exp((double)cL[0])) / l1, 1.0);
        }
    }
}

// ---------------------------------------------------------------------------
// S2: M[l][t][i][o] = W[o,i]*s[o] + sum_r A[i,r]B[r,o]  (f64 acc, f32 store)
// ---------------------------------------------------------------------------
__global__ __launch_bounds__(256) void setup2(
    const float* __restrict__ wF, const float* __restrict__ bF,
    const float* __restrict__ wH, const float* __restrict__ bH,
    const float* __restrict__ AF, const float* __restrict__ BFi,
    const float* __restrict__ HBi, const float* __restrict__ NSC,
    float* __restrict__ Mb, float* __restrict__ CBb)
{
    int b = blockIdx.x; int t = b / 49; int rem = b % 49;
    int o = threadIdx.x;
    int l, i0, ni;
    if (rem == 0) { l = 0; i0 = 0; ni = 3; }
    else { l = 1 + (rem - 1) / 16; i0 = ((rem - 1) % 16) * 16; ni = 16; }
    size_t ltb = (size_t)(l * 8 + t);
    const float* af = AF + ltb * 8192;
    const float* bf = BFi + ltb * 8192;
    double sc = (double)NSC[l * 256 + o];
    float bcol[32];
    #pragma unroll
    for (int r = 0; r < 32; ++r) bcol[r] = bf[r * 256 + o];
    for (int ii = 0; ii < ni; ++ii) {
        int i = i0 + ii;
        float wv = (l == 0) ? wF[o * 3 + i] : wH[(size_t)((l - 1) * 256 + o) * 256 + i];
        double m = (double)wv * sc;
        #pragma unroll
        for (int r = 0; r < 32; ++r)
            m = fma((double)af[i * 32 + r], (double)bcol[r], m);
        Mb[ltb * 65536 + (size_t)i * 256 + o] = (float)m;
    }
    if (rem == 0 || ((rem - 1) % 16) == 0) {
        double bb = (l == 0) ? (double)bF[o] : (double)bH[(l - 1) * 256 + o];
        CBb[ltb * 256 + o] = (float)(bb + (double)HBi[ltb * 256 + o]);
    }
}

// precise activation: sin(30*z) via f64 range reduction + f32 sin on [-pi,pi]
__device__ __forceinline__ float sin30(double z) {
    double u = z * C_30_OVER_2PI;
    double r = u - rint(u);
    return sinf((float)(r * C_2PI));
}

// ---------------------------------------------------------------------------
// L0: x = sin(30*(coords @ M0 + cb)), f64 per element (K=3).
// ---------------------------------------------------------------------------
__global__ __launch_bounds__(256) void layer0_k(
    const float* __restrict__ coords, const float* __restrict__ Mb,
    const float* __restrict__ CBb, float* __restrict__ X, int tbase)
{
    __shared__ float Ms[3][256];
    __shared__ float cbs[256];
    int tid = threadIdx.x;
    int tl = blockIdx.x >> 10; int rb = blockIdx.x & 1023;
    int t = tbase + tl;
    const float* Mt = Mb + (size_t)t * 65536;
    Ms[0][tid] = Mt[tid]; Ms[1][tid] = Mt[256 + tid]; Ms[2][tid] = Mt[512 + tid];
    cbs[tid] = CBb[t * 256 + tid];
    __syncthreads();
    int r = rb * 32 + (tid >> 3); int lane8 = tid & 7;
    const float* cp = coords + ((size_t)t * NPTS + r) * 3;
    double c0 = (double)cp[0], c1 = (double)cp[1], c2 = (double)cp[2];
    float* xo = X + ((size_t)tl * NPTS + r) * 256;
#define L0E(col) sin30(fma(c2, (double)Ms[2][col], fma(c1, (double)Ms[1][col], \
                  fma(c0, (double)Ms[0][col], (double)cbs[col]))))
    #pragma unroll
    for (int j = 0; j < 8; ++j) {
        int col = 4 * lane8 + 32 * j;
        float4 v;
        v.x = L0E(col + 0);
        v.y = L0E(col + 1);
        v.z = L0E(col + 2);
        v.w = L0E(col + 3);
        *(float4*)(xo + col) = v;
    }
#undef L0E
}

// ---------------------------------------------------------------------------
// Hidden layer via f64 MFMA: X[rows] = sin(30*(X @ M + cb)) IN PLACE.
// WG = 256 thr = 4 waves, tile 64 rows x 256 cols (full width -> in-place ok).
// A/B operand maps (trusted, uniform across CDNA): lane = 16*k + i.
// C/D layout: NOT assumed. Discovered at runtime by two probe MFMAs:
//   p1 = mfma(2^(lane&15), 1, 0)  -> D[m][n] = 4*2^m  -> reg r's ROW
//   p2 = mfma(1, 2^(lane&15), 0)  -> D[m][n] = 4*2^n  -> reg r's COL
// (exact powers of two in f64; decode = 61 - clzll). Round-5 failure
// (absmax 0.31) traced to the assumed D row map for the legacy f64 shape.
// LDS strides: As 72, Bs 264 -> all b32 fragment reads are 2-way (free, m136).
// ---------------------------------------------------------------------------
__global__ __launch_bounds__(256, 2) void gemm_sin(
    float* __restrict__ X, const float* __restrict__ Mb,
    const float* __restrict__ CBb, int l, int tbase)
{
    __shared__ float As[16][72];
    __shared__ float Bs[16][264];
    __shared__ float cbs[256];
    int tid = threadIdx.x;
    int tl = blockIdx.x >> 9; int rb = blockIdx.x & 511;
    size_t ltb = (size_t)(l * 8 + tbase + tl);
    const float* Mt = Mb + ltb * 65536;
    float* Xt = X + ((size_t)tl * NPTS + rb * 64) * 256;
    cbs[tid] = CBb[ltb * 256 + tid];
    int wave = tid >> 6, lane = tid & 63;
    int q = lane >> 4, c16 = lane & 15;
    // --- D-layout probe (layout-agnostic epilogue indices) ---
    v4d zz = {0., 0., 0., 0.};
    v4d p1 = __builtin_amdgcn_mfma_f64_16x16x4f64((double)(1 << c16), 1.0, zz, 0, 0, 0);
    v4d p2 = __builtin_amdgcn_mfma_f64_16x16x4f64(1.0, (double)(1 << c16), zz, 0, 0, 0);
    int r0 = 61 - __builtin_clzll((unsigned long long)p1[0]);
    int r1 = 61 - __builtin_clzll((unsigned long long)p1[1]);
    int r2 = 61 - __builtin_clzll((unsigned long long)p1[2]);
    int r3 = 61 - __builtin_clzll((unsigned long long)p1[3]);
    int c0 = 61 - __builtin_clzll((unsigned long long)p2[0]);
    int c1 = 61 - __builtin_clzll((unsigned long long)p2[1]);
    int c2 = 61 - __builtin_clzll((unsigned long long)p2[2]);
    int c3 = 61 - __builtin_clzll((unsigned long long)p2[3]);
    // staging indices
    int arow = tid >> 2;                // 0..63
    int ak4  = (tid & 3) * 4;
    int bch  = tid & 63;                // 16B chunk in B row
    int br0  = tid >> 6;                // 0..3 -> rows br0+{0,4,8,12}
    v4d acc0 = {0.,0.,0.,0.}, acc1 = {0.,0.,0.,0.}, acc2 = {0.,0.,0.,0.},
        acc3 = {0.,0.,0.,0.}, acc4 = {0.,0.,0.,0.}, acc5 = {0.,0.,0.,0.},
        acc6 = {0.,0.,0.,0.}, acc7 = {0.,0.,0.,0.}, acc8 = {0.,0.,0.,0.},
        acc9 = {0.,0.,0.,0.}, acc10 = {0.,0.,0.,0.}, acc11 = {0.,0.,0.,0.},
        acc12 = {0.,0.,0.,0.}, acc13 = {0.,0.,0.,0.}, acc14 = {0.,0.,0.,0.},
        acc15 = {0.,0.,0.,0.};
    for (int kb = 0; kb < 16; ++kb) {
        float4 a0 = *(const float4*)(Xt + (size_t)arow * 256 + kb * 16 + ak4);
        const float* Bg = Mt + (size_t)kb * 16 * 256 + bch * 4;
        float4 b0 = *(const float4*)(Bg + (br0 +  0) * 256);
        float4 b1 = *(const float4*)(Bg + (br0 +  4) * 256);
        float4 b2 = *(const float4*)(Bg + (br0 +  8) * 256);
        float4 b3 = *(const float4*)(Bg + (br0 + 12) * 256);
        __syncthreads();   // previous iter's LDS reads done before overwrite
        As[ak4+0][arow] = a0.x; As[ak4+1][arow] = a0.y;
        As[ak4+2][arow] = a0.z; As[ak4+3][arow] = a0.w;
        *(float4*)&Bs[br0 +  0][bch * 4] = b0;
        *(float4*)&Bs[br0 +  4][bch * 4] = b1;
        *(float4*)&Bs[br0 +  8][bch * 4] = b2;
        *(float4*)&Bs[br0 + 12][bch * 4] = b3;
        __syncthreads();
        #pragma unroll
        for (int k4 = 0; k4 < 4; ++k4) {
            int kk = k4 * 4 + q;
            double av = (double)As[kk][wave * 16 + c16];
#define TILE(n) { double bv = (double)Bs[kk][(n) * 16 + c16];                  \
                  acc##n = __builtin_amdgcn_mfma_f64_16x16x4f64(              \
                               av, bv, acc##n, 0, 0, 0); }
            TILE(0)  TILE(1)  TILE(2)  TILE(3)
            TILE(4)  TILE(5)  TILE(6)  TILE(7)
            TILE(8)  TILE(9)  TILE(10) TILE(11)
            TILE(12) TILE(13) TILE(14) TILE(15)
#undef TILE
        }
    }
    // epilogue: reg r of this lane holds D[row_r][col_r] of the wave's 16x16
    // tile n; global row = wave*16 + row_r, global col = n*16 + col_r.
    float* Xw = Xt + (size_t)(wave * 16) * 256;
#define EPT(n) {                                                               \
        int cb0 = (n) * 16;                                                    \
        Xw[r0 * 256 + cb0 + c0] = sin30(acc##n[0] + (double)cbs[cb0 + c0]);    \
        Xw[r1 * 256 + cb0 + c1] = sin30(acc##n[1] + (double)cbs[cb0 + c1]);    \
        Xw[r2 * 256 + cb0 + c2] = sin30(acc##n[2] + (double)cbs[cb0 + c2]);    \
        Xw[r3 * 256 + cb0 + c3] = sin30(acc##n[3] + (double)cbs[cb0 + c3]); }
    EPT(0)  EPT(1)  EPT(2)  EPT(3)
    EPT(4)  EPT(5)  EPT(6)  EPT(7)
    EPT(8)  EPT(9)  EPT(10) EPT(11)
    EPT(12) EPT(13) EPT(14) EPT(15)
#undef EPT
}

// ---------------------------------------------------------------------------
// Final: out[row] = (x_row . w_last)*scale + b_last, f64 dot. One wave per row.
// ---------------------------------------------------------------------------
__global__ __launch_bounds__(256) void final_k(
    const float* __restrict__ X, const float* __restrict__ wl,
    const float* __restrict__ bl, const float* __restrict__ NSC,
    float* __restrict__ out, int tbase)
{
    int tid = threadIdx.x; int w = tid >> 6; int lane = tid & 63;
    size_t row = (size_t)blockIdx.x * 4 + w;      // local row within 2 t's
    double ls = (double)NSC[1024];
    float4 wv = ((const float4*)wl)[lane];
    float4 xv = *(const float4*)(X + row * 256 + lane * 4);
    double d = 0.0;
    d = fma((double)wv.x, (double)xv.x, d);
    d = fma((double)wv.y, (double)xv.y, d);
    d = fma((double)wv.z, (double)xv.z, d);
    d = fma((double)wv.w, (double)xv.w, d);
    d *= ls;
    #pragma unroll
    for (int off = 32; off > 0; off >>= 1) d += __shfl_down(d, off, 64);
    if (lane == 0) out[(size_t)tbase * NPTS + row] = (float)(d + (double)bl[0]);
}

extern "C" void kernel_launch(void* const* d_in, const int* in_sizes, int n_in,
                              void* d_out, int out_size, void* d_ws, size_t ws_size,
                              hipStream_t stream)
{
    const float* coords     = (const float*)d_in[0];
    const float* latents    = (const float*)d_in[1];
    const float* nf_w_first = (const float*)d_in[2];
    const float* nf_b_first = (const float*)d_in[3];
    const float* nf_c_first = (const float*)d_in[4];
    const float* nf_w_hid   = (const float*)d_in[5];
    const float* nf_b_hid   = (const float*)d_in[6];
    const float* nf_c_hid   = (const float*)d_in[7];
    const float* nf_w_last  = (const float*)d_in[8];
    const float* nf_b_last  = (const float*)d_in[9];
    const float* nf_c_last  = (const float*)d_in[10];
    const float* Aw_first   = (const float*)d_in[11];
    const float* Ac_first   = (const float*)d_in[12];
    const float* Aw_hid     = (const float*)d_in[13];
    const float* Ac_hid     = (const float*)d_in[14];
    const float* Bw         = (const float*)d_in[15];
    const float* Bc         = (const float*)d_in[16];
    const float* hbw        = (const float*)d_in[17];
    const float* hbc        = (const float*)d_in[18];

    float* ws  = (float*)d_ws;
    float* Mb  = ws + OFF_M;
    float* CBb = ws + OFF_CB;
    float* AF  = ws + OFF_AF;
    float* BFb = ws + OFF_BF;
    float* HBb = ws + OFF_HB;
    float* NSC = ws + OFF_NSC;
    float* X   = ws + OFF_X;
    float* out = (float*)d_out;

    setup1<<<233, 256, 0, stream>>>(latents, Aw_first, Ac_first, Aw_hid, Ac_hid,
                                    Bw, Bc, hbw, hbc,
                                    nf_w_first, nf_c_first, nf_w_hid, nf_c_hid,
                                    nf_w_last, nf_c_last,
                                    AF, BFb, HBb, NSC);
    setup2<<<392, 256, 0, stream>>>(nf_w_first, nf_b_first, nf_w_hid, nf_b_hid,
                                    AF, BFb, HBb, NSC, Mb, CBb);
    for (int tbase = 0; tbase < 8; tbase += 2) {
        layer0_k<<<2048, 256, 0, stream>>>(coords, Mb, CBb, X, tbase);
        for (int l = 1; l <= 3; ++l)
            gemm_sin<<<1024, 256, 0, stream>>>(X, Mb, CBb, l, tbase);
        final_k<<<16384, 256, 0, stream>>>(X, nf_w_last, nf_b_last, NSC, out, tbase);
    }
}

// Round 7
// 2185.622 us; speedup vs baseline: 53.9902x; 1.0653x over previous
//
#include <hip/hip_runtime.h>
#include <math.h>

#define W0F 30.0f
#define NPTS 32768

// f64 sin-path constants: sin(30 z) = sin(2*pi*frac_centered(z * 30/(2*pi)))
#define C_30_OVER_2PI 4.774648292756860070
#define C_2PI         6.283185307179586477

typedef double v4d __attribute__((ext_vector_type(4)));

// ---- workspace layout (float offsets) ----
#define OFF_M    0ull                   // 4 layers * 8 t * 65536
#define SZ_M     2097152ull
#define OFF_CB   (OFF_M + SZ_M)         // 4*8*256
#define SZ_CB    8192ull
#define OFF_AF   (OFF_CB + SZ_CB)       // 4*8*8192
#define SZ_AF    262144ull
#define OFF_BF   (OFF_AF + SZ_AF)
#define SZ_BF    262144ull
#define OFF_HB   (OFF_BF + SZ_BF)       // 4*8*256
#define SZ_HB    8192ull
#define OFF_NSC  (OFF_HB + SZ_HB)       // 4*256 + 1, pad to 2048
#define SZ_NSC   2048ull
#define OFF_X    (OFF_NSC + SZ_NSC)     // 2*32768*256 floats (reused per t-pair)
#define SZ_X     16777216ull

// ---------------------------------------------------------------------------
// S1: per-row L1 scales + all latent-side GEMVs, f64 accumulation, f32 store.
// ---------------------------------------------------------------------------
__global__ __launch_bounds__(256) void setup1(
    const float* __restrict__ latents,
    const float* __restrict__ AwF, const float* __restrict__ AcF,
    const float* __restrict__ AwH, const float* __restrict__ AcH,
    const float* __restrict__ Bw,  const float* __restrict__ Bc,
    const float* __restrict__ hbw, const float* __restrict__ hbc,
    const float* __restrict__ wF,  const float* __restrict__ cF,
    const float* __restrict__ wH,  const float* __restrict__ cH,
    const float* __restrict__ wL,  const float* __restrict__ cL,
    float* __restrict__ AF, float* __restrict__ BFo,
    float* __restrict__ HBo, float* __restrict__ NSC)
{
    __shared__ float lat[1024];
    int tid = threadIdx.x;
    for (int j = tid; j < 1024; j += 256) lat[j] = latents[j];
    __syncthreads();
    int g = blockIdx.x * 256 + tid;
    if (g < 58464) {
        const float* src; float c; float* dst; int stride;
        if (g < 96) {
            src = AwF + g * 128; c = AcF[0]; dst = AF + g; stride = 8192;
        } else if (g < 24672) {
            int q = g - 96; int l = 1 + q / 8192;
            src = AwH + (size_t)q * 128; c = AcH[l - 1];
            dst = AF + (size_t)l * 8 * 8192 + (q % 8192); stride = 8192;
        } else if (g < 57440) {
            int q = g - 24672; int l = q / 8192;
            src = Bw + (size_t)q * 128; c = Bc[l];
            dst = BFo + (size_t)l * 8 * 8192 + (q % 8192); stride = 8192;
        } else {
            int q = g - 57440; int l = q / 256;
            src = hbw + (size_t)q * 128; c = hbc[l];
            dst = HBo + l * 8 * 256 + (q % 256); stride = 256;
        }
        double l1 = 0.0;
        double acc[8] = {0,0,0,0,0,0,0,0};
        for (int kk = 0; kk < 32; ++kk) {
            float4 w4 = ((const float4*)src)[kk];
            l1 += fabs((double)w4.x) + fabs((double)w4.y)
                + fabs((double)w4.z) + fabs((double)w4.w);
            int k = kk * 4;
            #pragma unroll
            for (int t = 0; t < 8; ++t) {
                const float* lp = &lat[t * 128 + k];
                acc[t] = fma((double)w4.x, (double)lp[0], acc[t]);
                acc[t] = fma((double)w4.y, (double)lp[1], acc[t]);
                acc[t] = fma((double)w4.z, (double)lp[2], acc[t]);
                acc[t] = fma((double)w4.w, (double)lp[3], acc[t]);
            }
        }
        double s = fmin(log1p(exp((double)c)) / l1, 1.0);
        #pragma unroll
        for (int t = 0; t < 8; ++t) dst[(size_t)t * stride] = (float)(acc[t] * s);
    } else if (g < 59489) {
        int h = g - 58464;
        if (h < 256) {
            const float* src = wF + h * 3;
            double l1 = fabs((double)src[0]) + fabs((double)src[1]) + fabs((double)src[2]);
            NSC[h] = (float)fmin(log1p(exp((double)cF[0])) / l1, 1.0);
        } else if (h < 1024) {
            int q = h - 256; int l = 1 + q / 256;
            const float* src = wH + (size_t)q * 256;
            double l1 = 0.0;
            for (int kk = 0; kk < 64; ++kk) {
                float4 w4 = ((const float4*)src)[kk];
                l1 += fabs((double)w4.x) + fabs((double)w4.y)
                    + fabs((double)w4.z) + fabs((double)w4.w);
            }
            NSC[256 + q] = (float)fmin(log1p(exp((double)cH[l - 1])) / l1, 1.0);
        } else {
            double l1 = 0.0;
            for (int kk = 0; kk < 64; ++kk) {
                float4 w4 = ((const float4*)wL)[kk];
                l1 += fabs((double)w4.x) + fabs((double)w4.y)
                    + fabs((double)w4.z) + fabs((double)w4.w);
            }
            NSC[1024] = (float)fmin(log1p(exp((double)cL[0])) / l1, 1.0);
        }
    }
}

// ---------------------------------------------------------------------------
// S2: M[l][t][i][o] = W[o,i]*s[o] + sum_r A[i,r]B[r,o]  (f64 acc, f32 store)
// ---------------------------------------------------------------------------
__global__ __launch_bounds__(256) void setup2(
    const float* __restrict__ wF, const float* __restrict__ bF,
    const float* __restrict__ wH, const float* __restrict__ bH,
    const float* __restrict__ AF, const float* __restrict__ BFi,
    const float* __restrict__ HBi, const float* __restrict__ NSC,
    float* __restrict__ Mb, float* __restrict__ CBb)
{
    int b = blockIdx.x; int t = b / 49; int rem = b % 49;
    int o = threadIdx.x;
    int l, i0, ni;
    if (rem == 0) { l = 0; i0 = 0; ni = 3; }
    else { l = 1 + (rem - 1) / 16; i0 = ((rem - 1) % 16) * 16; ni = 16; }
    size_t ltb = (size_t)(l * 8 + t);
    const float* af = AF + ltb * 8192;
    const float* bf = BFi + ltb * 8192;
    double sc = (double)NSC[l * 256 + o];
    float bcol[32];
    #pragma unroll
    for (int r = 0; r < 32; ++r) bcol[r] = bf[r * 256 + o];
    for (int ii = 0; ii < ni; ++ii) {
        int i = i0 + ii;
        float wv = (l == 0) ? wF[o * 3 + i] : wH[(size_t)((l - 1) * 256 + o) * 256 + i];
        double m = (double)wv * sc;
        #pragma unroll
        for (int r = 0; r < 32; ++r)
            m = fma((double)af[i * 32 + r], (double)bcol[r], m);
        Mb[ltb * 65536 + (size_t)i * 256 + o] = (float)m;
    }
    if (rem == 0 || ((rem - 1) % 16) == 0) {
        double bb = (l == 0) ? (double)bF[o] : (double)bH[(l - 1) * 256 + o];
        CBb[ltb * 256 + o] = (float)(bb + (double)HBi[ltb * 256 + o]);
    }
}

// precise activation: sin(30*z) via f64 range reduction + f32 sin on [-pi,pi]
__device__ __forceinline__ float sin30(double z) {
    double u = z * C_30_OVER_2PI;
    double r = u - rint(u);
    return sinf((float)(r * C_2PI));
}

// ---------------------------------------------------------------------------
// L0: x = sin(30*(coords @ M0 + cb)), f64 per element (K=3).
// ---------------------------------------------------------------------------
__global__ __launch_bounds__(256) void layer0_k(
    const float* __restrict__ coords, const float* __restrict__ Mb,
    const float* __restrict__ CBb, float* __restrict__ X, int tbase)
{
    __shared__ float Ms[3][256];
    __shared__ float cbs[256];
    int tid = threadIdx.x;
    int tl = blockIdx.x >> 10; int rb = blockIdx.x & 1023;
    int t = tbase + tl;
    const float* Mt = Mb + (size_t)t * 65536;
    Ms[0][tid] = Mt[tid]; Ms[1][tid] = Mt[256 + tid]; Ms[2][tid] = Mt[512 + tid];
    cbs[tid] = CBb[t * 256 + tid];
    __syncthreads();
    int r = rb * 32 + (tid >> 3); int lane8 = tid & 7;
    const float* cp = coords + ((size_t)t * NPTS + r) * 3;
    double c0 = (double)cp[0], c1 = (double)cp[1], c2 = (double)cp[2];
    float* xo = X + ((size_t)tl * NPTS + r) * 256;
#define L0E(col) sin30(fma(c2, (double)Ms[2][col], fma(c1, (double)Ms[1][col], \
                  fma(c0, (double)Ms[0][col], (double)cbs[col]))))
    #pragma unroll
    for (int j = 0; j < 8; ++j) {
        int col = 4 * lane8 + 32 * j;
        float4 v;
        v.x = L0E(col + 0);
        v.y = L0E(col + 1);
        v.z = L0E(col + 2);
        v.w = L0E(col + 3);
        *(float4*)(xo + col) = v;
    }
#undef L0E
}

// ---------------------------------------------------------------------------
// Hidden layer via f64 MFMA: X[rows] = sin(30*(X @ M + cb)) IN PLACE.
// WG = 256 thr = 4 waves, tile 64 rows x 256 cols (full width -> in-place ok).
// DOUBLE-BUFFERED LDS, ONE barrier per kb: prefetch kb+1 into regs, compute
// kb from buf[kb&1] (64 MFMAs ~ 4096 cyc hides the loads), store to the
// other buffer, single __syncthreads(). 3 blocks/CU (launch_bounds(256,3)):
// 152 regs <= 170 budget, 3 x 44 KB LDS <= 160 KB. Round-6 counters: the
// 2-barrier loop pinned MfmaUtil at 58% (= measured 57.5% pipe occupancy).
// C/D layout discovered at runtime by two probe MFMAs (round-5 lesson).
// ---------------------------------------------------------------------------
__global__ __launch_bounds__(256, 3) void gemm_sin(
    float* __restrict__ X, const float* __restrict__ Mb,
    const float* __restrict__ CBb, int l, int tbase)
{
    __shared__ float As[2][16][72];
    __shared__ float Bs[2][16][264];
    __shared__ float cbs[256];
    int tid = threadIdx.x;
    int tl = blockIdx.x >> 9; int rb = blockIdx.x & 511;
    size_t ltb = (size_t)(l * 8 + tbase + tl);
    const float* Mt = Mb + ltb * 65536;
    float* Xt = X + ((size_t)tl * NPTS + rb * 64) * 256;
    cbs[tid] = CBb[ltb * 256 + tid];
    int wave = tid >> 6, lane = tid & 63;
    int q = lane >> 4, c16 = lane & 15;
    // --- D-layout probe (layout-agnostic epilogue indices) ---
    v4d zz = {0., 0., 0., 0.};
    v4d p1 = __builtin_amdgcn_mfma_f64_16x16x4f64((double)(1 << c16), 1.0, zz, 0, 0, 0);
    v4d p2 = __builtin_amdgcn_mfma_f64_16x16x4f64(1.0, (double)(1 << c16), zz, 0, 0, 0);
    int r0 = 61 - __builtin_clzll((unsigned long long)p1[0]);
    int r1 = 61 - __builtin_clzll((unsigned long long)p1[1]);
    int r2 = 61 - __builtin_clzll((unsigned long long)p1[2]);
    int r3 = 61 - __builtin_clzll((unsigned long long)p1[3]);
    int c0 = 61 - __builtin_clzll((unsigned long long)p2[0]);
    int c1 = 61 - __builtin_clzll((unsigned long long)p2[1]);
    int c2 = 61 - __builtin_clzll((unsigned long long)p2[2]);
    int c3 = 61 - __builtin_clzll((unsigned long long)p2[3]);
    // staging indices
    int arow = tid >> 2;                // 0..63
    int ak4  = (tid & 3) * 4;
    int bch  = tid & 63;                // 16B chunk in B row
    int br0  = tid >> 6;                // 0..3 -> rows br0+{0,4,8,12}
    v4d acc0 = {0.,0.,0.,0.}, acc1 = {0.,0.,0.,0.}, acc2 = {0.,0.,0.,0.},
        acc3 = {0.,0.,0.,0.}, acc4 = {0.,0.,0.,0.}, acc5 = {0.,0.,0.,0.},
        acc6 = {0.,0.,0.,0.}, acc7 = {0.,0.,0.,0.}, acc8 = {0.,0.,0.,0.},
        acc9 = {0.,0.,0.,0.}, acc10 = {0.,0.,0.,0.}, acc11 = {0.,0.,0.,0.},
        acc12 = {0.,0.,0.,0.}, acc13 = {0.,0.,0.,0.}, acc14 = {0.,0.,0.,0.},
        acc15 = {0.,0.,0.,0.};
    // prologue: stage tile 0 into buffer 0
    {
        float4 a0 = *(const float4*)(Xt + (size_t)arow * 256 + ak4);
        const float* Bg = Mt + bch * 4;
        float4 b0 = *(const float4*)(Bg + (br0 +  0) * 256);
        float4 b1 = *(const float4*)(Bg + (br0 +  4) * 256);
        float4 b2 = *(const float4*)(Bg + (br0 +  8) * 256);
        float4 b3 = *(const float4*)(Bg + (br0 + 12) * 256);
        As[0][ak4+0][arow] = a0.x; As[0][ak4+1][arow] = a0.y;
        As[0][ak4+2][arow] = a0.z; As[0][ak4+3][arow] = a0.w;
        *(float4*)&Bs[0][br0 +  0][bch * 4] = b0;
        *(float4*)&Bs[0][br0 +  4][bch * 4] = b1;
        *(float4*)&Bs[0][br0 +  8][bch * 4] = b2;
        *(float4*)&Bs[0][br0 + 12][bch * 4] = b3;
    }
    __syncthreads();
    #pragma unroll 2
    for (int kb = 0; kb < 16; ++kb) {
        int cur = kb & 1, nxt = cur ^ 1;
        float4 a0, b0, b1, b2, b3;
        if (kb < 15) {   // prefetch next tile into registers
            a0 = *(const float4*)(Xt + (size_t)arow * 256 + (kb + 1) * 16 + ak4);
            const float* Bg = Mt + (size_t)(kb + 1) * 16 * 256 + bch * 4;
            b0 = *(const float4*)(Bg + (br0 +  0) * 256);
            b1 = *(const float4*)(Bg + (br0 +  4) * 256);
            b2 = *(const float4*)(Bg + (br0 +  8) * 256);
            b3 = *(const float4*)(Bg + (br0 + 12) * 256);
        }
        #pragma unroll
        for (int k4 = 0; k4 < 4; ++k4) {
            int kk = k4 * 4 + q;
            double av = (double)As[cur][kk][wave * 16 + c16];
#define TILE(n) { double bv = (double)Bs[cur][kk][(n) * 16 + c16];             \
                  acc##n = __builtin_amdgcn_mfma_f64_16x16x4f64(              \
                               av, bv, acc##n, 0, 0, 0); }
            TILE(0)  TILE(1)  TILE(2)  TILE(3)
            TILE(4)  TILE(5)  TILE(6)  TILE(7)
            TILE(8)  TILE(9)  TILE(10) TILE(11)
            TILE(12) TILE(13) TILE(14) TILE(15)
#undef TILE
        }
        if (kb < 15) {   // stage prefetched tile into the other buffer
            As[nxt][ak4+0][arow] = a0.x; As[nxt][ak4+1][arow] = a0.y;
            As[nxt][ak4+2][arow] = a0.z; As[nxt][ak4+3][arow] = a0.w;
            *(float4*)&Bs[nxt][br0 +  0][bch * 4] = b0;
            *(float4*)&Bs[nxt][br0 +  4][bch * 4] = b1;
            *(float4*)&Bs[nxt][br0 +  8][bch * 4] = b2;
            *(float4*)&Bs[nxt][br0 + 12][bch * 4] = b3;
        }
        __syncthreads();
    }
    // epilogue: reg r of this lane holds D[row_r][col_r] of the wave's 16x16
    // tile n; global row = wave*16 + row_r, global col = n*16 + col_r.
    float* Xw = Xt + (size_t)(wave * 16) * 256;
#define EPT(n) {                                                               \
        int cb0 = (n) * 16;                                                    \
        Xw[r0 * 256 + cb0 + c0] = sin30(acc##n[0] + (double)cbs[cb0 + c0]);    \
        Xw[r1 * 256 + cb0 + c1] = sin30(acc##n[1] + (double)cbs[cb0 + c1]);    \
        Xw[r2 * 256 + cb0 + c2] = sin30(acc##n[2] + (double)cbs[cb0 + c2]);    \
        Xw[r3 * 256 + cb0 + c3] = sin30(acc##n[3] + (double)cbs[cb0 + c3]); }
    EPT(0)  EPT(1)  EPT(2)  EPT(3)
    EPT(4)  EPT(5)  EPT(6)  EPT(7)
    EPT(8)  EPT(9)  EPT(10) EPT(11)
    EPT(12) EPT(13) EPT(14) EPT(15)
#undef EPT
}

// ---------------------------------------------------------------------------
// Final: out[row] = (x_row . w_last)*scale + b_last, f64 dot. One wave per row.
// ---------------------------------------------------------------------------
__global__ __launch_bounds__(256) void final_k(
    const float* __restrict__ X, const float* __restrict__ wl,
    const float* __restrict__ bl, const float* __restrict__ NSC,
    float* __restrict__ out, int tbase)
{
    int tid = threadIdx.x; int w = tid >> 6; int lane = tid & 63;
    size_t row = (size_t)blockIdx.x * 4 + w;      // local row within 2 t's
    double ls = (double)NSC[1024];
    float4 wv = ((const float4*)wl)[lane];
    float4 xv = *(const float4*)(X + row * 256 + lane * 4);
    double d = 0.0;
    d = fma((double)wv.x, (double)xv.x, d);
    d = fma((double)wv.y, (double)xv.y, d);
    d = fma((double)wv.z, (double)xv.z, d);
    d = fma((double)wv.w, (double)xv.w, d);
    d *= ls;
    #pragma unroll
    for (int off = 32; off > 0; off >>= 1) d += __shfl_down(d, off, 64);
    if (lane == 0) out[(size_t)tbase * NPTS + row] = (float)(d + (double)bl[0]);
}

extern "C" void kernel_launch(void* const* d_in, const int* in_sizes, int n_in,
                              void* d_out, int out_size, void* d_ws, size_t ws_size,
                              hipStream_t stream)
{
    const float* coords     = (const float*)d_in[0];
    const float* latents    = (const float*)d_in[1];
    const float* nf_w_first = (const float*)d_in[2];
    const float* nf_b_first = (const float*)d_in[3];
    const float* nf_c_first = (const float*)d_in[4];
    const float* nf_w_hid   = (const float*)d_in[5];
    const float* nf_b_hid   = (const float*)d_in[6];
    const float* nf_c_hid   = (const float*)d_in[7];
    const float* nf_w_last  = (const float*)d_in[8];
    const float* nf_b_last  = (const float*)d_in[9];
    const float* nf_c_last  = (const float*)d_in[10];
    const float* Aw_first   = (const float*)d_in[11];
    const float* Ac_first   = (const float*)d_in[12];
    const float* Aw_hid     = (const float*)d_in[13];
    const float* Ac_hid     = (const float*)d_in[14];
    const float* Bw         = (const float*)d_in[15];
    const float* Bc         = (const float*)d_in[16];
    const float* hbw        = (const float*)d_in[17];
    const float* hbc        = (const float*)d_in[18];

    float* ws  = (float*)d_ws;
    float* Mb  = ws + OFF_M;
    float* CBb = ws + OFF_CB;
    float* AF  = ws + OFF_AF;
    float* BFb = ws + OFF_BF;
    float* HBb = ws + OFF_HB;
    float* NSC = ws + OFF_NSC;
    float* X   = ws + OFF_X;
    float* out = (float*)d_out;

    setup1<<<233, 256, 0, stream>>>(latents, Aw_first, Ac_first, Aw_hid, Ac_hid,
                                    Bw, Bc, hbw, hbc,
                                    nf_w_first, nf_c_first, nf_w_hid, nf_c_hid,
                                    nf_w_last, nf_c_last,
                                    AF, BFb, HBb, NSC);
    setup2<<<392, 256, 0, stream>>>(nf_w_first, nf_b_first, nf_w_hid, nf_b_hid,
                                    AF, BFb, HBb, NSC, Mb, CBb);
    for (int tbase = 0; tbase < 8; tbase += 2) {
        layer0_k<<<2048, 256, 0, stream>>>(coords, Mb, CBb, X, tbase);
        for (int l = 1; l <= 3; ++l)
            gemm_sin<<<1024, 256, 0, stream>>>(X, Mb, CBb, l, tbase);
        final_k<<<16384, 256, 0, stream>>>(X, nf_w_last, nf_b_last, NSC, out, tbase);
    }
}